// Round 1
// baseline (721.188 us; speedup 1.0000x reference)
//
#include <hip/hip_runtime.h>

#define N_ATOMS 100000
#define M_NBRS 12
#define ATOM_F 64
#define NBR_F 41
#define OUT_DIM 128   // 2*ATOM_F
#define IN_DIM 169    // 2*ATOM_F + NBR_F
#define N_GROUPS (N_ATOMS / 16)   // 6250, exact

typedef __attribute__((ext_vector_type(8))) short short8;
typedef __attribute__((ext_vector_type(4))) float f32x4;
typedef __attribute__((ext_vector_type(2))) unsigned u32x2;
typedef __attribute__((ext_vector_type(4))) unsigned u32x4;

__device__ __forceinline__ unsigned short f2bf(float f) {
    union { float f; unsigned u; } v; v.f = f;
    unsigned u = v.u;
    return (unsigned short)((u + 0x7fffu + ((u >> 16) & 1u)) >> 16);
}
// packed f32x2 -> bf16x2 (RNE): lo16 = bf16(a), hi16 = bf16(b). 1 VALU inst.
__device__ __forceinline__ unsigned cvt_pk(float a, float b) {
    unsigned r;
    asm("v_cvt_pk_bf16_f32 %0, %1, %2" : "=v"(r) : "v"(a), "v"(b));
    return r;
}
__device__ __forceinline__ float softplus_f(float x) {
    return fmaxf(x, 0.f) + __logf(1.f + __expf(-fabsf(x)));
}
__device__ __forceinline__ float sigmoid_f(float x) {
    // __fdividef -> v_rcp based; avoids the precise div_scale/div_fmas sequence
    return __fdividef(1.f, 1.f + __expf(-x));
}

// ---------------------------------------------------------------------------
// P: per-atom precompute.
//   abf[a]  = bf16(atom_fea[a])                       (N*32 u32)
//   A1P[a][c*4+p] = u32{ lo=bf16(Wself·a + b)[p*16+c], hi=...[64+p*16+c] }
// i.e. A1 pre-packed (filter,core) pairs in exactly the lane layout k_msg
// consumes (one uint4 per (row, c-lane)).  Also zeroes the BN stat buffer.
// ---------------------------------------------------------------------------
#define WS_STRIDE 72   // bf16 stride for Ws rows (144B, 16B-aligned)
__global__ __launch_bounds__(256, 4) void k_prep(
    const float* __restrict__ atom, const float* __restrict__ W,
    const float* __restrict__ bias, unsigned* __restrict__ abf_u32,
    unsigned* __restrict__ A1P, float* __restrict__ SUM)
{
    __shared__ unsigned short Ws[128 * WS_STRIDE];   // W_self bf16 [col][k]
    __shared__ unsigned Ap[4 * 16 * 36];             // per-wave A tile
    __shared__ unsigned T2[4][16 * 68];              // per-wave packed A1 tile
    const int tid = threadIdx.x;
    const int w = tid >> 6, l = tid & 63;
    const int r = l & 15, g = l >> 4;

    if (blockIdx.x == 0 && tid < 128) SUM[tid] = 0.f;

    // stage W_self -> LDS bf16 (coalesced reads)
    for (int e = tid; e < 128 * 64; e += 256) {
        int col = e >> 6, k = e & 63;
        Ws[col * WS_STRIDE + k] = f2bf(W[col * IN_DIM + k]);
    }
    __syncthreads();

    short8 bf[8][2];
    #pragma unroll
    for (int nt = 0; nt < 8; ++nt)
      #pragma unroll
      for (int kk = 0; kk < 2; ++kk) {
            int col = nt * 16 + r;
            union { u32x4 u; short8 s; } u;
            u.u = *reinterpret_cast<const u32x4*>(&Ws[col * WS_STRIDE + kk * 32 + g * 8]);
            bf[nt][kk] = u.s;
      }
    float bb[8];
    #pragma unroll
    for (int nt = 0; nt < 8; ++nt) bb[nt] = bias[nt * 16 + r];

    const int totalw = gridDim.x * 4;
    const int gw = blockIdx.x * 4 + w;
    const int step = totalw * 16;
    const int T = (N_ATOMS + step - 1) / step;
    unsigned* Aw = &Ap[w * 16 * 36];
    unsigned* Tw = T2[w];

    for (int t = 0; t < T; ++t) {
        int base = gw * 16 + t * step;
        // load 16 atoms x 64 f32 -> bf16 pack -> Aw
        #pragma unroll
        for (int sub = 0; sub < 4; ++sub) {
            int chunk = g * 4 + sub;
            int a = base + r;
            float4 v = make_float4(0.f, 0.f, 0.f, 0.f);
            if (a < N_ATOMS)
                v = reinterpret_cast<const float4*>(atom)[a * 16 + chunk];
            Aw[r * 36 + chunk * 2]     = cvt_pk(v.x, v.y);
            Aw[r * 36 + chunk * 2 + 1] = cvt_pk(v.z, v.w);
        }
        // coalesced abf store
        {
            int al = l >> 2, part = l & 3;
            int a = base + al;
            if (a < N_ATOMS) {
                u32x4 d0 = *reinterpret_cast<const u32x4*>(&Aw[al * 36 + part * 8]);
                u32x4 d1 = *reinterpret_cast<const u32x4*>(&Aw[al * 36 + part * 8 + 4]);
                *reinterpret_cast<u32x4*>(&abf_u32[(size_t)a * 32 + part * 8]) = d0;
                *reinterpret_cast<u32x4*>(&abf_u32[(size_t)a * 32 + part * 8 + 4]) = d1;
            }
        }
        short8 af[2];
        #pragma unroll
        for (int kk = 0; kk < 2; ++kk) {
            union { u32x4 u; short8 s; } u;
            u.u = *reinterpret_cast<const u32x4*>(&Aw[r * 36 + kk * 16 + g * 4]);
            af[kk] = u.s;
        }
        // filter (nt) and core (nt+4) together -> packed u32 tile
        #pragma unroll
        for (int nt = 0; nt < 4; ++nt) {
            f32x4 accf = {0.f,0.f,0.f,0.f}, accc = {0.f,0.f,0.f,0.f};
            accf = __builtin_amdgcn_mfma_f32_16x16x32_bf16(af[0], bf[nt][0],   accf, 0,0,0);
            accf = __builtin_amdgcn_mfma_f32_16x16x32_bf16(af[1], bf[nt][1],   accf, 0,0,0);
            accc = __builtin_amdgcn_mfma_f32_16x16x32_bf16(af[0], bf[nt+4][0], accc, 0,0,0);
            accc = __builtin_amdgcn_mfma_f32_16x16x32_bf16(af[1], bf[nt+4][1], accc, 0,0,0);
            #pragma unroll
            for (int r4 = 0; r4 < 4; ++r4) {
                int row = g * 4 + r4;    // C row = atom within tile
                // A1P col-layout: q = c*4 + p  (c = r here, p = nt)
                Tw[row * 68 + r * 4 + nt] = cvt_pk(accf[r4] + bb[nt], accc[r4] + bb[nt + 4]);
            }
        }
        // coalesced A1P store: lane l -> atom l>>2, quarter l&3 (16 u32 each)
        {
            int al = l >> 2, part = l & 3;
            int a = base + al;
            if (a < N_ATOMS) {
                #pragma unroll
                for (int q = 0; q < 4; ++q) {
                    u32x4 d = *reinterpret_cast<const u32x4*>(&Tw[al * 68 + part * 16 + q * 4]);
                    *reinterpret_cast<u32x4*>(&A1P[(size_t)a * 64 + part * 16 + q * 4]) = d;
                }
            }
        }
    }
}

// ---------------------------------------------------------------------------
// M: 16 atoms per wave-group, 12 MFMA tiles (one per neighbor slot).
// Tile rows = 16 atoms (no pad rows), neighbor sum accumulates in registers
// across tiles (no reduction shuffles, no masked epilogue).  Software
// pipeline: idx 2 tiles ahead, gather/edge data 1 tile ahead.  Barrier-free
// main loop (wave-private LDS tile aliased into the dead W-staging buffer).
// BN partial stats accumulated in-kernel -> 128 atomics per block.
// ---------------------------------------------------------------------------
#define BS_STRIDE 136   // bf16 stride for Bs rows (272B, 16B-aligned)

struct TBuf { u32x2 ga[4]; float f0[4], f1[4], f2[4], f3[4]; };

__device__ __forceinline__ TBuf load_data(
    const unsigned* __restrict__ abf, const float* __restrict__ nbr,
    int base, int m, const int* jj, int c, int g)
{
    TBuf b;
    #pragma unroll
    for (int rr = 0; rr < 4; ++rr) {
        // gathered nbr-atom bf16: u32 cols {2c,2c+1} of row rr*4+g
        b.ga[rr] = *reinterpret_cast<const u32x2*>(abf + (size_t)jj[rr] * 32 + 2 * c);
        // raw edge floats 4c..4c+3 (41 per row; tail lanes masked)
        const float* ep = nbr + ((size_t)(base + rr * 4 + g) * M_NBRS + m) * NBR_F + 4 * c;
        bool c10 = (c < 10);
        b.f0[rr] = (c < 11) ? ep[0] : 0.f;
        b.f1[rr] = c10 ? ep[1] : 0.f;
        b.f2[rr] = c10 ? ep[2] : 0.f;
        b.f3[rr] = c10 ? ep[3] : 0.f;
    }
    return b;
}

__global__ __launch_bounds__(256, 2) void k_msg(
    const float* __restrict__ atom, const float* __restrict__ nbr,
    const float* __restrict__ W, const int* __restrict__ idx,
    const unsigned* __restrict__ abf, const unsigned* __restrict__ A1P,
    float* __restrict__ X, float* __restrict__ SUM)
{
    __shared__ __align__(16) unsigned short Bs[128 * BS_STRIDE]; // 34816 B
    const int tid = threadIdx.x;
    const int w = tid >> 6, l = tid & 63;
    const int c = l & 15, g = l >> 4;
    // after B-frag read, Bs is dead: alias per-wave A tiles into it
    unsigned* Aw = reinterpret_cast<unsigned*>(Bs) + w * 16 * 68;  // 4352 B/wave

    // zero Bs (covers K-pad 105..127 and row pad)
    for (int e = tid; e < 128 * BS_STRIDE / 2; e += 256)
        reinterpret_cast<unsigned*>(Bs)[e] = 0u;
    __syncthreads();
    // stage W_nbr|W_edge -> LDS bf16 (coalesced reads)
    for (int e = tid; e < 128 * 105; e += 256) {
        unsigned col = (unsigned)e / 105u;
        unsigned k = (unsigned)e - col * 105u;
        Bs[col * BS_STRIDE + k] = f2bf(W[col * IN_DIM + 64 + k]);
    }
    __syncthreads();

    // B fragments -> registers (held whole kernel, 128 regs -> AGPR)
    short8 bf[8][4];
    #pragma unroll
    for (int nt = 0; nt < 8; ++nt)
      #pragma unroll
      for (int kk = 0; kk < 4; ++kk) {
            int col = nt * 16 + c;
            union { u32x4 u; short8 s; } u;
            u.u = *reinterpret_cast<const u32x4*>(&Bs[col * BS_STRIDE + kk * 32 + g * 8]);
            bf[nt][kk] = u.s;
      }
    __syncthreads();   // everyone done reading Bs before Aw overwrites it

    const int TW = gridDim.x * 4;
    const int gw = blockIdx.x * 4 + w;
    float sum_p[4] = {0.f,0.f,0.f,0.f}, sq_p[4] = {0.f,0.f,0.f,0.f};

    #pragma unroll 1
    for (int grp = gw; grp < N_GROUPS; grp += TW) {
        const int base = grp * 16;   // N_ATOMS % 16 == 0: no row masking
        // A1 packed pairs for the 16 output rows this lane owns
        u32x4 a1q[4];
        #pragma unroll
        for (int r4 = 0; r4 < 4; ++r4)
            a1q[r4] = *reinterpret_cast<const u32x4*>(
                &A1P[(size_t)(base + g * 4 + r4) * 64 + c * 4]);

        float gs[4][4];
        #pragma unroll
        for (int r4 = 0; r4 < 4; ++r4)
          #pragma unroll
          for (int p = 0; p < 4; ++p) gs[r4][p] = 0.f;

        // ---- pipeline warm-up: j(0)+data(0), j(1) ----
        int jn[4];
        TBuf buf;
        {
            int j0[4];
            #pragma unroll
            for (int rr = 0; rr < 4; ++rr)
                j0[rr] = idx[(base + rr * 4 + g) * M_NBRS + 0];
            buf = load_data(abf, nbr, base, 0, j0, c, g);
        }
        #pragma unroll
        for (int rr = 0; rr < 4; ++rr)
            jn[rr] = idx[(base + rr * 4 + g) * M_NBRS + 1];

        #pragma unroll 4
        for (int m = 0; m < M_NBRS; ++m) {
            // ---- stage tile m (b64 writes, cvt_pk edge pack) ----
            #pragma unroll
            for (int rr = 0; rr < 4; ++rr) {
                int r = rr * 4 + g;
                *reinterpret_cast<u32x2*>(Aw + r * 68 + 2 * c) = buf.ga[rr];
                u32x2 e;
                e[0] = cvt_pk(buf.f0[rr], buf.f1[rr]);
                e[1] = cvt_pk(buf.f2[rr], buf.f3[rr]);
                *reinterpret_cast<u32x2*>(Aw + r * 68 + 32 + 2 * c) = e;
            }
            // ---- prefetch tile m+1 data, tile m+2 indices ----
            if (m + 1 < M_NBRS) {
                buf = load_data(abf, nbr, base, m + 1, jn, c, g);
                if (m + 2 < M_NBRS) {
                    #pragma unroll
                    for (int rr = 0; rr < 4; ++rr)
                        jn[rr] = idx[(base + rr * 4 + g) * M_NBRS + m + 2];
                }
            }
            // ---- compute tile m ----
            short8 af[4];
            #pragma unroll
            for (int kk = 0; kk < 4; ++kk) {
                union { u32x4 u; short8 s; } u;
                u.u = *reinterpret_cast<const u32x4*>(&Aw[c * 68 + kk * 16 + g * 4]);
                af[kk] = u.s;
            }
            #pragma unroll
            for (int p = 0; p < 4; ++p) {
                f32x4 accf = {0.f,0.f,0.f,0.f}, accc = {0.f,0.f,0.f,0.f};
                #pragma unroll
                for (int kk = 0; kk < 4; ++kk) {
                    accf = __builtin_amdgcn_mfma_f32_16x16x32_bf16(af[kk], bf[p][kk],     accf, 0,0,0);
                    accc = __builtin_amdgcn_mfma_f32_16x16x32_bf16(af[kk], bf[p + 4][kk], accc, 0,0,0);
                }
                #pragma unroll
                for (int r4 = 0; r4 < 4; ++r4) {
                    unsigned a1 = a1q[r4][p];
                    float zf = accf[r4] + __uint_as_float(a1 << 16);
                    float zc = accc[r4] + __uint_as_float(a1 & 0xffff0000u);
                    gs[r4][p] += sigmoid_f(zf) * softplus_f(zc);
                }
            }
        }
        // ---- epilogue: x = atom + msg, store, accumulate BN partials ----
        #pragma unroll
        for (int r4 = 0; r4 < 4; ++r4) {
            int o = (base + g * 4 + r4) * ATOM_F + c;
            #pragma unroll
            for (int p = 0; p < 4; ++p) {
                float x = atom[o + p * 16] + gs[r4][p];
                X[o + p * 16] = x;
                sum_p[p] += x;
                sq_p[p] += x * x;
            }
        }
    }

    // ---- BN stats: wave reduce over g, block reduce over waves, 1 atomic ----
    #pragma unroll
    for (int p = 0; p < 4; ++p) {
        sum_p[p] += __shfl_xor(sum_p[p], 16, 64);
        sum_p[p] += __shfl_xor(sum_p[p], 32, 64);
        sq_p[p]  += __shfl_xor(sq_p[p], 16, 64);
        sq_p[p]  += __shfl_xor(sq_p[p], 32, 64);
    }
    __syncthreads();   // all waves done with their Aw before reusing LDS
    float* Rs = reinterpret_cast<float*>(Bs);
    if (g == 0) {
        #pragma unroll
        for (int p = 0; p < 4; ++p) {
            Rs[w * 128 + p * 16 + c] = sum_p[p];
            Rs[512 + w * 128 + p * 16 + c] = sq_p[p];
        }
    }
    __syncthreads();
    if (tid < 128) {
        int q = tid & 63;
        int o = (tid >> 6) * 512;
        float v = Rs[o + q] + Rs[o + 128 + q] + Rs[o + 256 + q] + Rs[o + 384 + q];
        atomicAdd(&SUM[tid], v);
    }
}

// ---------------------------------------------------------------------------
// BN scale/shift from accumulated stats, then in-place normalize + softplus.
// ---------------------------------------------------------------------------
__global__ void k_stats2(const float* __restrict__ SUM, const float* __restrict__ gamma,
                         const float* __restrict__ beta, float* __restrict__ MS)
{
    int t = threadIdx.x;   // 64 threads
    float mean = SUM[t] * (1.f / N_ATOMS);
    float msq  = SUM[64 + t] * (1.f / N_ATOMS);
    float var  = msq - mean * mean;        // biased var, matches jnp.var
    float inv  = rsqrtf(var + 1e-5f);
    float sc   = inv * gamma[t];
    float sh   = beta[t] - mean * sc;
    MS[t] = sc;
    MS[64 + t] = sh;
}

__global__ void k_final(float* __restrict__ X, const float* __restrict__ MS)
{
    int q = blockIdx.x * 256 + threadIdx.x;   // exactly N*64/4 threads
    const float4* MS4 = reinterpret_cast<const float4*>(MS);
    float4 x = reinterpret_cast<const float4*>(X)[q];
    float4 sc = MS4[q & 15];
    float4 sh = MS4[16 + (q & 15)];
    float4 o;
    o.x = softplus_f(x.x * sc.x + sh.x);
    o.y = softplus_f(x.y * sc.y + sh.y);
    o.z = softplus_f(x.z * sc.z + sh.z);
    o.w = softplus_f(x.w * sc.w + sh.w);
    reinterpret_cast<float4*>(X)[q] = o;
}

extern "C" void kernel_launch(void* const* d_in, const int* in_sizes, int n_in,
                              void* d_out, int out_size, void* d_ws, size_t ws_size,
                              hipStream_t stream)
{
    const float* atom  = (const float*)d_in[0];
    const float* nbr   = (const float*)d_in[1];
    const float* W     = (const float*)d_in[2];
    const float* bias  = (const float*)d_in[3];
    const float* gamma = (const float*)d_in[4];
    const float* beta  = (const float*)d_in[5];
    const int*   idx   = (const int*)d_in[6];
    float* X = (float*)d_out;   // x pre-BN lives in d_out, finalized in place

    char* ws = (char*)d_ws;
    unsigned* abf = (unsigned*)ws;                                     // N*32 u32
    unsigned* A1P = (unsigned*)(ws + (size_t)N_ATOMS * 32 * 4);        // N*64 u32
    float* SUM    = (float*)(ws + (size_t)N_ATOMS * 32 * 4
                                + (size_t)N_ATOMS * 64 * 4);           // 128 f32
    float* MS     = SUM + 128;                                         // 128 f32

    hipLaunchKernelGGL(k_prep,   dim3(512),  dim3(256), 0, stream, atom, W, bias, abf, A1P, SUM);
    hipLaunchKernelGGL(k_msg,    dim3(512),  dim3(256), 0, stream, atom, nbr, W, idx, abf, A1P, X, SUM);
    hipLaunchKernelGGL(k_stats2, dim3(1),    dim3(64),  0, stream, SUM, gamma, beta, MS);
    hipLaunchKernelGGL(k_final,  dim3(6250), dim3(256), 0, stream, X, MS);
}

// Round 2
// 548.755 us; speedup vs baseline: 1.3142x; 1.3142x over previous
//
#include <hip/hip_runtime.h>

#define N_ATOMS 100000
#define M_NBRS 12
#define ATOM_F 64
#define NBR_F 41
#define OUT_DIM 128   // 2*ATOM_F
#define IN_DIM 169    // 2*ATOM_F + NBR_F
#define N_GROUPS (N_ATOMS / 16)   // 6250, exact

typedef __attribute__((ext_vector_type(8))) short short8;
typedef __attribute__((ext_vector_type(4))) float f32x4;
typedef __attribute__((ext_vector_type(2))) unsigned u32x2;
typedef __attribute__((ext_vector_type(4))) unsigned u32x4;

__device__ __forceinline__ unsigned short f2bf(float f) {
    union { float f; unsigned u; } v; v.f = f;
    unsigned u = v.u;
    return (unsigned short)((u + 0x7fffu + ((u >> 16) & 1u)) >> 16);
}
// packed f32x2 -> bf16x2 (RNE): lo16 = bf16(a), hi16 = bf16(b). 1 VALU inst.
__device__ __forceinline__ unsigned cvt_pk(float a, float b) {
    unsigned r;
    asm("v_cvt_pk_bf16_f32 %0, %1, %2" : "=v"(r) : "v"(a), "v"(b));
    return r;
}
__device__ __forceinline__ float softplus_f(float x) {
    return fmaxf(x, 0.f) + __logf(1.f + __expf(-fabsf(x)));
}
__device__ __forceinline__ float sigmoid_f(float x) {
    // __fdividef -> v_rcp based; avoids the precise div_scale/div_fmas sequence
    return __fdividef(1.f, 1.f + __expf(-x));
}

// ---------------------------------------------------------------------------
// P: per-atom precompute.
//   abf[a]  = bf16(atom_fea[a])                       (N*32 u32)
//   A1P[a][c*4+p] = u32{ lo=bf16(Wself·a + b)[p*16+c], hi=...[64+p*16+c] }
// i.e. A1 pre-packed (filter,core) pairs in exactly the lane layout k_msg
// consumes (one uint4 per (row, c-lane)).  Also zeroes the BN stat buffer.
// ---------------------------------------------------------------------------
#define WS_STRIDE 72   // bf16 stride for Ws rows (144B, 16B-aligned)
__global__ __launch_bounds__(256, 4) void k_prep(
    const float* __restrict__ atom, const float* __restrict__ W,
    const float* __restrict__ bias, unsigned* __restrict__ abf_u32,
    unsigned* __restrict__ A1P, float* __restrict__ SUM)
{
    __shared__ unsigned short Ws[128 * WS_STRIDE];   // W_self bf16 [col][k]
    __shared__ unsigned Ap[4 * 16 * 36];             // per-wave A tile
    __shared__ unsigned T2[4][16 * 68];              // per-wave packed A1 tile
    const int tid = threadIdx.x;
    const int w = tid >> 6, l = tid & 63;
    const int r = l & 15, g = l >> 4;

    if (blockIdx.x == 0 && tid < 128) SUM[tid] = 0.f;

    // stage W_self -> LDS bf16 (coalesced reads)
    for (int e = tid; e < 128 * 64; e += 256) {
        int col = e >> 6, k = e & 63;
        Ws[col * WS_STRIDE + k] = f2bf(W[col * IN_DIM + k]);
    }
    __syncthreads();

    short8 bf[8][2];
    #pragma unroll
    for (int nt = 0; nt < 8; ++nt)
      #pragma unroll
      for (int kk = 0; kk < 2; ++kk) {
            int col = nt * 16 + r;
            union { u32x4 u; short8 s; } u;
            u.u = *reinterpret_cast<const u32x4*>(&Ws[col * WS_STRIDE + kk * 32 + g * 8]);
            bf[nt][kk] = u.s;
      }
    float bb[8];
    #pragma unroll
    for (int nt = 0; nt < 8; ++nt) bb[nt] = bias[nt * 16 + r];

    const int totalw = gridDim.x * 4;
    const int gw = blockIdx.x * 4 + w;
    const int step = totalw * 16;
    const int T = (N_ATOMS + step - 1) / step;
    unsigned* Aw = &Ap[w * 16 * 36];
    unsigned* Tw = T2[w];

    for (int t = 0; t < T; ++t) {
        int base = gw * 16 + t * step;
        // load 16 atoms x 64 f32 -> bf16 pack -> Aw
        #pragma unroll
        for (int sub = 0; sub < 4; ++sub) {
            int chunk = g * 4 + sub;
            int a = base + r;
            float4 v = make_float4(0.f, 0.f, 0.f, 0.f);
            if (a < N_ATOMS)
                v = reinterpret_cast<const float4*>(atom)[a * 16 + chunk];
            Aw[r * 36 + chunk * 2]     = cvt_pk(v.x, v.y);
            Aw[r * 36 + chunk * 2 + 1] = cvt_pk(v.z, v.w);
        }
        // coalesced abf store
        {
            int al = l >> 2, part = l & 3;
            int a = base + al;
            if (a < N_ATOMS) {
                u32x4 d0 = *reinterpret_cast<const u32x4*>(&Aw[al * 36 + part * 8]);
                u32x4 d1 = *reinterpret_cast<const u32x4*>(&Aw[al * 36 + part * 8 + 4]);
                *reinterpret_cast<u32x4*>(&abf_u32[(size_t)a * 32 + part * 8]) = d0;
                *reinterpret_cast<u32x4*>(&abf_u32[(size_t)a * 32 + part * 8 + 4]) = d1;
            }
        }
        short8 af[2];
        #pragma unroll
        for (int kk = 0; kk < 2; ++kk) {
            union { u32x4 u; short8 s; } u;
            u.u = *reinterpret_cast<const u32x4*>(&Aw[r * 36 + kk * 16 + g * 4]);
            af[kk] = u.s;
        }
        // filter (nt) and core (nt+4) together -> packed u32 tile
        #pragma unroll
        for (int nt = 0; nt < 4; ++nt) {
            f32x4 accf = {0.f,0.f,0.f,0.f}, accc = {0.f,0.f,0.f,0.f};
            accf = __builtin_amdgcn_mfma_f32_16x16x32_bf16(af[0], bf[nt][0],   accf, 0,0,0);
            accf = __builtin_amdgcn_mfma_f32_16x16x32_bf16(af[1], bf[nt][1],   accf, 0,0,0);
            accc = __builtin_amdgcn_mfma_f32_16x16x32_bf16(af[0], bf[nt+4][0], accc, 0,0,0);
            accc = __builtin_amdgcn_mfma_f32_16x16x32_bf16(af[1], bf[nt+4][1], accc, 0,0,0);
            #pragma unroll
            for (int r4 = 0; r4 < 4; ++r4) {
                int row = g * 4 + r4;    // C row = atom within tile
                // A1P col-layout: q = c*4 + p  (c = r here, p = nt)
                Tw[row * 68 + r * 4 + nt] = cvt_pk(accf[r4] + bb[nt], accc[r4] + bb[nt + 4]);
            }
        }
        // coalesced A1P store: lane l -> atom l>>2, quarter l&3 (16 u32 each)
        {
            int al = l >> 2, part = l & 3;
            int a = base + al;
            if (a < N_ATOMS) {
                #pragma unroll
                for (int q = 0; q < 4; ++q) {
                    u32x4 d = *reinterpret_cast<const u32x4*>(&Tw[al * 68 + part * 16 + q * 4]);
                    *reinterpret_cast<u32x4*>(&A1P[(size_t)a * 64 + part * 16 + q * 4]) = d;
                }
            }
        }
    }
}

// ---------------------------------------------------------------------------
// M: 16 atoms per wave-group, 12 MFMA tiles (one per neighbor slot).
// Tile rows = 16 atoms (no pad rows), neighbor sum accumulates in registers
// across tiles.  Software pipeline: idx 2 tiles ahead, gather/edge data 1
// tile ahead.  m-loop is unroll(1): with bf[8][4] pinning 128 AGPRs the
// VGPR budget is 128 (launch_bounds 256,2) — unroll(4) doubled live
// pipeline state and spilled to scratch (round-1: WRITE_SIZE 25->148 MB,
// FETCH 192 MB->1.04 GB, dur 220->483 us).  A1 rides in as the MFMA C-init.
// BN partial stats accumulated in-kernel -> 128 atomics per block.
// ---------------------------------------------------------------------------
#define BS_STRIDE 136   // bf16 stride for Bs rows (272B, 16B-aligned)

struct TBuf { u32x2 ga[4]; float f0[4], f1[4], f2[4], f3[4]; };

__device__ __forceinline__ TBuf load_data(
    const unsigned* __restrict__ abf, const float* __restrict__ nbr,
    int base, int m, const int* jj, int c, int g)
{
    TBuf b;
    #pragma unroll
    for (int rr = 0; rr < 4; ++rr) {
        // gathered nbr-atom bf16: u32 cols {2c,2c+1} of row rr*4+g
        b.ga[rr] = *reinterpret_cast<const u32x2*>(abf + (size_t)jj[rr] * 32 + 2 * c);
        // raw edge floats 4c..4c+3 (41 per row; tail lanes masked)
        const float* ep = nbr + ((size_t)(base + rr * 4 + g) * M_NBRS + m) * NBR_F + 4 * c;
        bool c10 = (c < 10);
        b.f0[rr] = (c < 11) ? ep[0] : 0.f;
        b.f1[rr] = c10 ? ep[1] : 0.f;
        b.f2[rr] = c10 ? ep[2] : 0.f;
        b.f3[rr] = c10 ? ep[3] : 0.f;
    }
    return b;
}

__global__ __launch_bounds__(256, 2) void k_msg(
    const float* __restrict__ atom, const float* __restrict__ nbr,
    const float* __restrict__ W, const int* __restrict__ idx,
    const unsigned* __restrict__ abf, const unsigned* __restrict__ A1P,
    float* __restrict__ X, float* __restrict__ SUM)
{
    __shared__ __align__(16) unsigned short Bs[128 * BS_STRIDE]; // 34816 B
    const int tid = threadIdx.x;
    const int w = tid >> 6, l = tid & 63;
    const int c = l & 15, g = l >> 4;
    // after B-frag read, Bs is dead: alias per-wave A tiles into it
    unsigned* Aw = reinterpret_cast<unsigned*>(Bs) + w * 16 * 68;  // 4352 B/wave

    // zero Bs (covers K-pad 105..127 and row pad)
    for (int e = tid; e < 128 * BS_STRIDE / 2; e += 256)
        reinterpret_cast<unsigned*>(Bs)[e] = 0u;
    __syncthreads();
    // stage W_nbr|W_edge -> LDS bf16 (coalesced reads)
    for (int e = tid; e < 128 * 105; e += 256) {
        unsigned col = (unsigned)e / 105u;
        unsigned k = (unsigned)e - col * 105u;
        Bs[col * BS_STRIDE + k] = f2bf(W[col * IN_DIM + 64 + k]);
    }
    __syncthreads();

    // B fragments -> registers (held whole kernel, 128 regs -> AGPR)
    short8 bf[8][4];
    #pragma unroll
    for (int nt = 0; nt < 8; ++nt)
      #pragma unroll
      for (int kk = 0; kk < 4; ++kk) {
            int col = nt * 16 + c;
            union { u32x4 u; short8 s; } u;
            u.u = *reinterpret_cast<const u32x4*>(&Bs[col * BS_STRIDE + kk * 32 + g * 8]);
            bf[nt][kk] = u.s;
      }
    __syncthreads();   // everyone done reading Bs before Aw overwrites it

    const int TW = gridDim.x * 4;
    const int gw = blockIdx.x * 4 + w;
    float sum_p[4] = {0.f,0.f,0.f,0.f}, sq_p[4] = {0.f,0.f,0.f,0.f};

    #pragma unroll 1
    for (int grp = gw; grp < N_GROUPS; grp += TW) {
        const int base = grp * 16;   // N_ATOMS % 16 == 0: no row masking
        // A1 packed pairs for the 16 output rows this lane owns
        u32x4 a1q[4];
        #pragma unroll
        for (int r4 = 0; r4 < 4; ++r4)
            a1q[r4] = *reinterpret_cast<const u32x4*>(
                &A1P[(size_t)(base + g * 4 + r4) * 64 + c * 4]);

        float gs[4][4];
        #pragma unroll
        for (int r4 = 0; r4 < 4; ++r4)
          #pragma unroll
          for (int p = 0; p < 4; ++p) gs[r4][p] = 0.f;

        // ---- pipeline warm-up: j(0)+data(0), j(1) ----
        int jn[4];
        TBuf buf;
        {
            int j0[4];
            #pragma unroll
            for (int rr = 0; rr < 4; ++rr)
                j0[rr] = idx[(base + rr * 4 + g) * M_NBRS + 0];
            buf = load_data(abf, nbr, base, 0, j0, c, g);
        }
        #pragma unroll
        for (int rr = 0; rr < 4; ++rr)
            jn[rr] = idx[(base + rr * 4 + g) * M_NBRS + 1];

        #pragma unroll 1
        for (int m = 0; m < M_NBRS; ++m) {
            // ---- stage tile m (b64 writes, cvt_pk edge pack) ----
            #pragma unroll
            for (int rr = 0; rr < 4; ++rr) {
                int r = rr * 4 + g;
                *reinterpret_cast<u32x2*>(Aw + r * 68 + 2 * c) = buf.ga[rr];
                u32x2 e;
                e[0] = cvt_pk(buf.f0[rr], buf.f1[rr]);
                e[1] = cvt_pk(buf.f2[rr], buf.f3[rr]);
                *reinterpret_cast<u32x2*>(Aw + r * 68 + 32 + 2 * c) = e;
            }
            // ---- prefetch tile m+1 data, tile m+2 indices ----
            if (m + 1 < M_NBRS) {
                buf = load_data(abf, nbr, base, m + 1, jn, c, g);
                if (m + 2 < M_NBRS) {
                    #pragma unroll
                    for (int rr = 0; rr < 4; ++rr)
                        jn[rr] = idx[(base + rr * 4 + g) * M_NBRS + m + 2];
                }
            }
            // ---- compute tile m ----
            short8 af[4];
            #pragma unroll
            for (int kk = 0; kk < 4; ++kk) {
                union { u32x4 u; short8 s; } u;
                u.u = *reinterpret_cast<const u32x4*>(&Aw[c * 68 + kk * 16 + g * 4]);
                af[kk] = u.s;
            }
            #pragma unroll
            for (int p = 0; p < 4; ++p) {
                // A1 (self-term) rides in as the accumulator init
                f32x4 accf, accc;
                #pragma unroll
                for (int r4 = 0; r4 < 4; ++r4) {
                    unsigned a1 = a1q[r4][p];
                    accf[r4] = __uint_as_float(a1 << 16);
                    accc[r4] = __uint_as_float(a1 & 0xffff0000u);
                }
                #pragma unroll
                for (int kk = 0; kk < 4; ++kk) {
                    accf = __builtin_amdgcn_mfma_f32_16x16x32_bf16(af[kk], bf[p][kk],     accf, 0,0,0);
                    accc = __builtin_amdgcn_mfma_f32_16x16x32_bf16(af[kk], bf[p + 4][kk], accc, 0,0,0);
                }
                #pragma unroll
                for (int r4 = 0; r4 < 4; ++r4)
                    gs[r4][p] += sigmoid_f(accf[r4]) * softplus_f(accc[r4]);
            }
        }
        // ---- epilogue: x = atom + msg, store, accumulate BN partials ----
        #pragma unroll
        for (int r4 = 0; r4 < 4; ++r4) {
            int o = (base + g * 4 + r4) * ATOM_F + c;
            #pragma unroll
            for (int p = 0; p < 4; ++p) {
                float x = atom[o + p * 16] + gs[r4][p];
                X[o + p * 16] = x;
                sum_p[p] += x;
                sq_p[p] += x * x;
            }
        }
    }

    // ---- BN stats: wave reduce over g, block reduce over waves, 1 atomic ----
    #pragma unroll
    for (int p = 0; p < 4; ++p) {
        sum_p[p] += __shfl_xor(sum_p[p], 16, 64);
        sum_p[p] += __shfl_xor(sum_p[p], 32, 64);
        sq_p[p]  += __shfl_xor(sq_p[p], 16, 64);
        sq_p[p]  += __shfl_xor(sq_p[p], 32, 64);
    }
    __syncthreads();   // all waves done with their Aw before reusing LDS
    float* Rs = reinterpret_cast<float*>(Bs);
    if (g == 0) {
        #pragma unroll
        for (int p = 0; p < 4; ++p) {
            Rs[w * 128 + p * 16 + c] = sum_p[p];
            Rs[512 + w * 128 + p * 16 + c] = sq_p[p];
        }
    }
    __syncthreads();
    if (tid < 128) {
        int q = tid & 63;
        int o = (tid >> 6) * 512;
        float v = Rs[o + q] + Rs[o + 128 + q] + Rs[o + 256 + q] + Rs[o + 384 + q];
        atomicAdd(&SUM[tid], v);
    }
}

// ---------------------------------------------------------------------------
// BN scale/shift from accumulated stats, then in-place normalize + softplus.
// ---------------------------------------------------------------------------
__global__ void k_stats2(const float* __restrict__ SUM, const float* __restrict__ gamma,
                         const float* __restrict__ beta, float* __restrict__ MS)
{
    int t = threadIdx.x;   // 64 threads
    float mean = SUM[t] * (1.f / N_ATOMS);
    float msq  = SUM[64 + t] * (1.f / N_ATOMS);
    float var  = msq - mean * mean;        // biased var, matches jnp.var
    float inv  = rsqrtf(var + 1e-5f);
    float sc   = inv * gamma[t];
    float sh   = beta[t] - mean * sc;
    MS[t] = sc;
    MS[64 + t] = sh;
}

__global__ void k_final(float* __restrict__ X, const float* __restrict__ MS)
{
    int q = blockIdx.x * 256 + threadIdx.x;   // exactly N*64/4 threads
    const float4* MS4 = reinterpret_cast<const float4*>(MS);
    float4 x = reinterpret_cast<const float4*>(X)[q];
    float4 sc = MS4[q & 15];
    float4 sh = MS4[16 + (q & 15)];
    float4 o;
    o.x = softplus_f(x.x * sc.x + sh.x);
    o.y = softplus_f(x.y * sc.y + sh.y);
    o.z = softplus_f(x.z * sc.z + sh.z);
    o.w = softplus_f(x.w * sc.w + sh.w);
    reinterpret_cast<float4*>(X)[q] = o;
}

extern "C" void kernel_launch(void* const* d_in, const int* in_sizes, int n_in,
                              void* d_out, int out_size, void* d_ws, size_t ws_size,
                              hipStream_t stream)
{
    const float* atom  = (const float*)d_in[0];
    const float* nbr   = (const float*)d_in[1];
    const float* W     = (const float*)d_in[2];
    const float* bias  = (const float*)d_in[3];
    const float* gamma = (const float*)d_in[4];
    const float* beta  = (const float*)d_in[5];
    const int*   idx   = (const int*)d_in[6];
    float* X = (float*)d_out;   // x pre-BN lives in d_out, finalized in place

    char* ws = (char*)d_ws;
    unsigned* abf = (unsigned*)ws;                                     // N*32 u32
    unsigned* A1P = (unsigned*)(ws + (size_t)N_ATOMS * 32 * 4);        // N*64 u32
    float* SUM    = (float*)(ws + (size_t)N_ATOMS * 32 * 4
                                + (size_t)N_ATOMS * 64 * 4);           // 128 f32
    float* MS     = SUM + 128;                                         // 128 f32

    hipLaunchKernelGGL(k_prep,   dim3(512),  dim3(256), 0, stream, atom, W, bias, abf, A1P, SUM);
    hipLaunchKernelGGL(k_msg,    dim3(512),  dim3(256), 0, stream, atom, nbr, W, idx, abf, A1P, X, SUM);
    hipLaunchKernelGGL(k_stats2, dim3(1),    dim3(64),  0, stream, SUM, gamma, beta, MS);
    hipLaunchKernelGGL(k_final,  dim3(6250), dim3(256), 0, stream, X, MS);
}

// Round 3
// 414.534 us; speedup vs baseline: 1.7398x; 1.3238x over previous
//
#include <hip/hip_runtime.h>

#define N_ATOMS 100000
#define M_NBRS 12
#define ATOM_F 64
#define NBR_F 41
#define OUT_DIM 128   // 2*ATOM_F
#define IN_DIM 169    // 2*ATOM_F + NBR_F
#define N_GROUPS (N_ATOMS / 16)   // 6250, exact

typedef __attribute__((ext_vector_type(8))) short short8;
typedef __attribute__((ext_vector_type(4))) float f32x4;
typedef __attribute__((ext_vector_type(2))) unsigned u32x2;
typedef __attribute__((ext_vector_type(4))) unsigned u32x4;

__device__ __forceinline__ unsigned short f2bf(float f) {
    union { float f; unsigned u; } v; v.f = f;
    unsigned u = v.u;
    return (unsigned short)((u + 0x7fffu + ((u >> 16) & 1u)) >> 16);
}
// packed f32x2 -> bf16x2 (RNE): lo16 = bf16(a), hi16 = bf16(b). 1 VALU inst.
__device__ __forceinline__ unsigned cvt_pk(float a, float b) {
    unsigned r;
    asm("v_cvt_pk_bf16_f32 %0, %1, %2" : "=v"(r) : "v"(a), "v"(b));
    return r;
}
__device__ __forceinline__ float softplus_f(float x) {
    return fmaxf(x, 0.f) + __logf(1.f + __expf(-fabsf(x)));
}
__device__ __forceinline__ float sigmoid_f(float x) {
    return __fdividef(1.f, 1.f + __expf(-x));
}

// ---------------------------------------------------------------------------
// P: per-atom precompute.
//   abf[a]  = bf16(atom_fea[a])                       (N*32 u32)
//   A1P[a][c*4+p] = u32{ lo=bf16(Wself·a + b)[p*16+c], hi=...[64+p*16+c] }
// Pre-packed (filter,core) pairs in exactly the lane layout k_msg consumes.
// Also zeroes the BN stat buffer.
// ---------------------------------------------------------------------------
#define WS_STRIDE 72   // bf16 stride for Ws rows (144B, 16B-aligned)
__global__ __launch_bounds__(256, 4) void k_prep(
    const float* __restrict__ atom, const float* __restrict__ W,
    const float* __restrict__ bias, unsigned* __restrict__ abf_u32,
    unsigned* __restrict__ A1P, float* __restrict__ SUM)
{
    __shared__ unsigned short Ws[128 * WS_STRIDE];   // W_self bf16 [col][k]
    __shared__ unsigned Ap[4 * 16 * 36];             // per-wave A tile
    __shared__ unsigned T2[4][16 * 68];              // per-wave packed A1 tile
    const int tid = threadIdx.x;
    const int w = tid >> 6, l = tid & 63;
    const int r = l & 15, g = l >> 4;

    if (blockIdx.x == 0 && tid < 128) SUM[tid] = 0.f;

    // stage W_self -> LDS bf16 (coalesced reads)
    for (int e = tid; e < 128 * 64; e += 256) {
        int col = e >> 6, k = e & 63;
        Ws[col * WS_STRIDE + k] = f2bf(W[col * IN_DIM + k]);
    }
    __syncthreads();

    short8 bf[8][2];
    #pragma unroll
    for (int nt = 0; nt < 8; ++nt)
      #pragma unroll
      for (int kk = 0; kk < 2; ++kk) {
            int col = nt * 16 + r;
            union { u32x4 u; short8 s; } u;
            u.u = *reinterpret_cast<const u32x4*>(&Ws[col * WS_STRIDE + kk * 32 + g * 8]);
            bf[nt][kk] = u.s;
      }
    float bb[8];
    #pragma unroll
    for (int nt = 0; nt < 8; ++nt) bb[nt] = bias[nt * 16 + r];

    const int totalw = gridDim.x * 4;
    const int gw = blockIdx.x * 4 + w;
    const int step = totalw * 16;
    const int T = (N_ATOMS + step - 1) / step;
    unsigned* Aw = &Ap[w * 16 * 36];
    unsigned* Tw = T2[w];

    for (int t = 0; t < T; ++t) {
        int base = gw * 16 + t * step;
        // load 16 atoms x 64 f32 -> bf16 pack -> Aw
        #pragma unroll
        for (int sub = 0; sub < 4; ++sub) {
            int chunk = g * 4 + sub;
            int a = base + r;
            float4 v = make_float4(0.f, 0.f, 0.f, 0.f);
            if (a < N_ATOMS)
                v = reinterpret_cast<const float4*>(atom)[a * 16 + chunk];
            Aw[r * 36 + chunk * 2]     = cvt_pk(v.x, v.y);
            Aw[r * 36 + chunk * 2 + 1] = cvt_pk(v.z, v.w);
        }
        // coalesced abf store
        {
            int al = l >> 2, part = l & 3;
            int a = base + al;
            if (a < N_ATOMS) {
                u32x4 d0 = *reinterpret_cast<const u32x4*>(&Aw[al * 36 + part * 8]);
                u32x4 d1 = *reinterpret_cast<const u32x4*>(&Aw[al * 36 + part * 8 + 4]);
                *reinterpret_cast<u32x4*>(&abf_u32[(size_t)a * 32 + part * 8]) = d0;
                *reinterpret_cast<u32x4*>(&abf_u32[(size_t)a * 32 + part * 8 + 4]) = d1;
            }
        }
        short8 af[2];
        #pragma unroll
        for (int kk = 0; kk < 2; ++kk) {
            union { u32x4 u; short8 s; } u;
            u.u = *reinterpret_cast<const u32x4*>(&Aw[r * 36 + kk * 16 + g * 4]);
            af[kk] = u.s;
        }
        // filter (nt) and core (nt+4) together -> packed u32 tile
        #pragma unroll
        for (int nt = 0; nt < 4; ++nt) {
            f32x4 accf = {0.f,0.f,0.f,0.f}, accc = {0.f,0.f,0.f,0.f};
            accf = __builtin_amdgcn_mfma_f32_16x16x32_bf16(af[0], bf[nt][0],   accf, 0,0,0);
            accf = __builtin_amdgcn_mfma_f32_16x16x32_bf16(af[1], bf[nt][1],   accf, 0,0,0);
            accc = __builtin_amdgcn_mfma_f32_16x16x32_bf16(af[0], bf[nt+4][0], accc, 0,0,0);
            accc = __builtin_amdgcn_mfma_f32_16x16x32_bf16(af[1], bf[nt+4][1], accc, 0,0,0);
            #pragma unroll
            for (int r4 = 0; r4 < 4; ++r4) {
                int row = g * 4 + r4;    // C row = atom within tile
                Tw[row * 68 + r * 4 + nt] = cvt_pk(accf[r4] + bb[nt], accc[r4] + bb[nt + 4]);
            }
        }
        // coalesced A1P store
        {
            int al = l >> 2, part = l & 3;
            int a = base + al;
            if (a < N_ATOMS) {
                #pragma unroll
                for (int q = 0; q < 4; ++q) {
                    u32x4 d = *reinterpret_cast<const u32x4*>(&Tw[al * 68 + part * 16 + q * 4]);
                    *reinterpret_cast<u32x4*>(&A1P[(size_t)a * 64 + part * 16 + q * 4]) = d;
                }
            }
        }
    }
}

// ---------------------------------------------------------------------------
// M: one 16-atom group per wave (grid 1563 -> perfect balance), 12 MFMA
// tiles (one per neighbor slot), neighbor sum accumulates in registers.
// B is NOT register-pinned: fragments are re-read from LDS per tile
// (MfmaUtil was 5% -- matrix pipe has slack; pinning cost 128 regs, caused
// spills at the 128-VGPR cap, and capped occupancy at 2 waves/SIMD.
// Round-2 evidence: WRITE_SIZE 94 MB vs 26 ideal).  Opaque-asm on the B
// byte-offset blocks LICM from hoisting the 32 ds_read_b128 out of the
// m-loop.  launch_bounds(256,3): LDS 52.2KB -> 3 blocks/CU, ~170-reg cap.
// Software pipeline: gather/edge data 1 tile ahead, idx 2 ahead.
// A1 rides in as MFMA C-init.  BN stats fused (128 atomics per block).
// ---------------------------------------------------------------------------
#define BS_STRIDE 136   // bf16 stride for Bs rows (272B, 16B-aligned)

struct TBuf { u32x2 ga[4]; float f0[4], f1[4], f2[4], f3[4]; };

__device__ __forceinline__ TBuf load_data(
    const unsigned* __restrict__ abf, const float* __restrict__ nbr,
    int base, int m, const int* jj, int c, int g)
{
    TBuf b;
    #pragma unroll
    for (int rr = 0; rr < 4; ++rr) {
        // gathered nbr-atom bf16: u32 cols {2c,2c+1} of row rr*4+g
        b.ga[rr] = *reinterpret_cast<const u32x2*>(abf + (size_t)jj[rr] * 32 + 2 * c);
        // raw edge floats 4c..4c+3 (41 per row; tail lanes masked)
        const float* ep = nbr + ((size_t)(base + rr * 4 + g) * M_NBRS + m) * NBR_F + 4 * c;
        bool c10 = (c < 10);
        b.f0[rr] = (c < 11) ? ep[0] : 0.f;
        b.f1[rr] = c10 ? ep[1] : 0.f;
        b.f2[rr] = c10 ? ep[2] : 0.f;
        b.f3[rr] = c10 ? ep[3] : 0.f;
    }
    return b;
}

__global__ __launch_bounds__(256, 3) void k_msg(
    const float* __restrict__ atom, const float* __restrict__ nbr,
    const float* __restrict__ W, const int* __restrict__ idx,
    const unsigned* __restrict__ abf, const unsigned* __restrict__ A1P,
    float* __restrict__ X, float* __restrict__ SUM)
{
    __shared__ __align__(16) unsigned short Bs[128 * BS_STRIDE]; // 34816 B, persistent
    __shared__ __align__(16) unsigned Au[4 * 16 * 68];           // 17408 B per-wave tiles
    const int tid = threadIdx.x;
    const int w = tid >> 6, l = tid & 63;
    const int c = l & 15, g = l >> 4;
    unsigned* Aw = &Au[w * 16 * 68];

    // zero Bs (covers K-pad 105..127)
    for (int e = tid; e < 128 * BS_STRIDE / 2; e += 256)
        reinterpret_cast<unsigned*>(Bs)[e] = 0u;
    __syncthreads();
    // stage W_nbr|W_edge -> LDS bf16 (coalesced reads; L3-resident re-fetch)
    for (int e = tid; e < 128 * 105; e += 256) {
        unsigned col = (unsigned)e / 105u;
        unsigned k = (unsigned)e - col * 105u;
        Bs[col * BS_STRIDE + k] = f2bf(W[col * IN_DIM + 64 + k]);
    }
    __syncthreads();

    const int gw = blockIdx.x * 4 + w;
    float sum_p[4] = {0.f,0.f,0.f,0.f}, sq_p[4] = {0.f,0.f,0.f,0.f};

    if (gw < N_GROUPS) {
        const int base = gw * 16;
        // A1 packed pairs for the 16 outputs this lane owns
        u32x4 a1q[4];
        #pragma unroll
        for (int r4 = 0; r4 < 4; ++r4)
            a1q[r4] = *reinterpret_cast<const u32x4*>(
                &A1P[(size_t)(base + g * 4 + r4) * 64 + c * 4]);

        float gs[4][4];
        #pragma unroll
        for (int r4 = 0; r4 < 4; ++r4)
          #pragma unroll
          for (int p = 0; p < 4; ++p) gs[r4][p] = 0.f;

        // per-lane byte offset into Bs for fragment reads; made opaque each
        // m-iter so LICM cannot hoist the 32 ds_read_b128 (would pin 128 regs)
        unsigned bofs = (unsigned)(c * BS_STRIDE + g * 8) * 2u;

        // ---- pipeline warm-up: j(0)+data(0), j(1) ----
        int jn[4];
        TBuf buf;
        {
            int j0[4];
            #pragma unroll
            for (int rr = 0; rr < 4; ++rr)
                j0[rr] = idx[(base + rr * 4 + g) * M_NBRS + 0];
            buf = load_data(abf, nbr, base, 0, j0, c, g);
        }
        #pragma unroll
        for (int rr = 0; rr < 4; ++rr)
            jn[rr] = idx[(base + rr * 4 + g) * M_NBRS + 1];

        #pragma unroll 1
        for (int m = 0; m < M_NBRS; ++m) {
            asm volatile("" : "+v"(bofs));   // block LICM of B-fragment reads
            // ---- stage tile m (b64 writes, cvt_pk edge pack) ----
            #pragma unroll
            for (int rr = 0; rr < 4; ++rr) {
                int r = rr * 4 + g;
                *reinterpret_cast<u32x2*>(Aw + r * 68 + 2 * c) = buf.ga[rr];
                u32x2 e;
                e[0] = cvt_pk(buf.f0[rr], buf.f1[rr]);
                e[1] = cvt_pk(buf.f2[rr], buf.f3[rr]);
                *reinterpret_cast<u32x2*>(Aw + r * 68 + 32 + 2 * c) = e;
            }
            // ---- prefetch tile m+1 data, tile m+2 indices ----
            if (m + 1 < M_NBRS) {
                buf = load_data(abf, nbr, base, m + 1, jn, c, g);
                if (m + 2 < M_NBRS) {
                    #pragma unroll
                    for (int rr = 0; rr < 4; ++rr)
                        jn[rr] = idx[(base + rr * 4 + g) * M_NBRS + m + 2];
                }
            }
            // ---- compute tile m ----
            short8 af[4];
            #pragma unroll
            for (int kk = 0; kk < 4; ++kk) {
                union { u32x4 u; short8 s; } u;
                u.u = *reinterpret_cast<const u32x4*>(&Aw[c * 68 + kk * 16 + g * 4]);
                af[kk] = u.s;
            }
            const char* bsb = reinterpret_cast<const char*>(Bs);
            #pragma unroll
            for (int p = 0; p < 4; ++p) {
                // A1 (self-term) rides in as the accumulator init
                f32x4 accf, accc;
                #pragma unroll
                for (int r4 = 0; r4 < 4; ++r4) {
                    unsigned a1 = a1q[r4][p];
                    accf[r4] = __uint_as_float(a1 << 16);
                    accc[r4] = __uint_as_float(a1 & 0xffff0000u);
                }
                #pragma unroll
                for (int kk = 0; kk < 4; ++kk) {
                    union { u32x4 u; short8 s; } uf, uc;
                    uf.u = *reinterpret_cast<const u32x4*>(
                        bsb + bofs + (p * 16 * BS_STRIDE + kk * 32) * 2);
                    uc.u = *reinterpret_cast<const u32x4*>(
                        bsb + bofs + ((p + 4) * 16 * BS_STRIDE + kk * 32) * 2);
                    accf = __builtin_amdgcn_mfma_f32_16x16x32_bf16(af[kk], uf.s, accf, 0,0,0);
                    accc = __builtin_amdgcn_mfma_f32_16x16x32_bf16(af[kk], uc.s, accc, 0,0,0);
                }
                #pragma unroll
                for (int r4 = 0; r4 < 4; ++r4)
                    gs[r4][p] += sigmoid_f(accf[r4]) * softplus_f(accc[r4]);
            }
        }
        // ---- epilogue: x = atom + msg, store, accumulate BN partials ----
        #pragma unroll
        for (int r4 = 0; r4 < 4; ++r4) {
            int o = (base + g * 4 + r4) * ATOM_F + c;
            #pragma unroll
            for (int p = 0; p < 4; ++p) {
                float x = atom[o + p * 16] + gs[r4][p];
                X[o + p * 16] = x;
                sum_p[p] += x;
                sq_p[p] += x * x;
            }
        }
    }

    // ---- BN stats: wave reduce over g, block reduce over waves, 1 atomic ----
    #pragma unroll
    for (int p = 0; p < 4; ++p) {
        sum_p[p] += __shfl_xor(sum_p[p], 16, 64);
        sum_p[p] += __shfl_xor(sum_p[p], 32, 64);
        sq_p[p]  += __shfl_xor(sq_p[p], 16, 64);
        sq_p[p]  += __shfl_xor(sq_p[p], 32, 64);
    }
    __syncthreads();   // all waves done reading Bs before reuse as scratch
    float* Rs = reinterpret_cast<float*>(Bs);
    if (g == 0) {
        #pragma unroll
        for (int p = 0; p < 4; ++p) {
            Rs[w * 128 + p * 16 + c] = sum_p[p];
            Rs[512 + w * 128 + p * 16 + c] = sq_p[p];
        }
    }
    __syncthreads();
    if (tid < 128) {
        int q = tid & 63;
        int o = (tid >> 6) * 512;
        float v = Rs[o + q] + Rs[o + 128 + q] + Rs[o + 256 + q] + Rs[o + 384 + q];
        atomicAdd(&SUM[tid], v);
    }
}

// ---------------------------------------------------------------------------
// BN scale/shift from accumulated stats, then in-place normalize + softplus.
// ---------------------------------------------------------------------------
__global__ void k_stats2(const float* __restrict__ SUM, const float* __restrict__ gamma,
                         const float* __restrict__ beta, float* __restrict__ MS)
{
    int t = threadIdx.x;   // 64 threads
    float mean = SUM[t] * (1.f / N_ATOMS);
    float msq  = SUM[64 + t] * (1.f / N_ATOMS);
    float var  = msq - mean * mean;        // biased var, matches jnp.var
    float inv  = rsqrtf(var + 1e-5f);
    float sc   = inv * gamma[t];
    float sh   = beta[t] - mean * sc;
    MS[t] = sc;
    MS[64 + t] = sh;
}

__global__ void k_final(float* __restrict__ X, const float* __restrict__ MS)
{
    int q = blockIdx.x * 256 + threadIdx.x;   // exactly N*64/4 threads
    const float4* MS4 = reinterpret_cast<const float4*>(MS);
    float4 x = reinterpret_cast<const float4*>(X)[q];
    float4 sc = MS4[q & 15];
    float4 sh = MS4[16 + (q & 15)];
    float4 o;
    o.x = softplus_f(x.x * sc.x + sh.x);
    o.y = softplus_f(x.y * sc.y + sh.y);
    o.z = softplus_f(x.z * sc.z + sh.z);
    o.w = softplus_f(x.w * sc.w + sh.w);
    reinterpret_cast<float4*>(X)[q] = o;
}

extern "C" void kernel_launch(void* const* d_in, const int* in_sizes, int n_in,
                              void* d_out, int out_size, void* d_ws, size_t ws_size,
                              hipStream_t stream)
{
    const float* atom  = (const float*)d_in[0];
    const float* nbr   = (const float*)d_in[1];
    const float* W     = (const float*)d_in[2];
    const float* bias  = (const float*)d_in[3];
    const float* gamma = (const float*)d_in[4];
    const float* beta  = (const float*)d_in[5];
    const int*   idx   = (const int*)d_in[6];
    float* X = (float*)d_out;   // x pre-BN lives in d_out, finalized in place

    char* ws = (char*)d_ws;
    unsigned* abf = (unsigned*)ws;                                     // N*32 u32
    unsigned* A1P = (unsigned*)(ws + (size_t)N_ATOMS * 32 * 4);        // N*64 u32
    float* SUM    = (float*)(ws + (size_t)N_ATOMS * 32 * 4
                                + (size_t)N_ATOMS * 64 * 4);           // 128 f32
    float* MS     = SUM + 128;                                         // 128 f32

    const int msg_blocks = (N_GROUPS + 3) / 4;   // 1563: one group per wave
    hipLaunchKernelGGL(k_prep,   dim3(512),        dim3(256), 0, stream, atom, W, bias, abf, A1P, SUM);
    hipLaunchKernelGGL(k_msg,    dim3(msg_blocks), dim3(256), 0, stream, atom, nbr, W, idx, abf, A1P, X, SUM);
    hipLaunchKernelGGL(k_stats2, dim3(1),          dim3(64),  0, stream, SUM, gamma, beta, MS);
    hipLaunchKernelGGL(k_final,  dim3(6250),       dim3(256), 0, stream, X, MS);
}